// Round 14
// baseline (258.109 us; speedup 1.0000x reference)
//
#include <hip/hip_runtime.h>
#include <math.h>

#define NPTS 262144
#define PTS  16
#define NBLK (NPTS / PTS)   // 16384 blocks, 128 threads (2 waves) each
#define AP   136            // activation pitch in f16: 272 B -> b128-aligned rows, uniform bank spread

typedef _Float16 f16;
typedef f16    f16x4 __attribute__((ext_vector_type(4)));
typedef f16    f16x8 __attribute__((ext_vector_type(8)));
typedef __fp16 h16x2 __attribute__((ext_vector_type(2)));
typedef __fp16 h16x4 __attribute__((ext_vector_type(4)));
typedef float  f32x4 __attribute__((ext_vector_type(4)));

// MFMA 16x16x32 f16, weights as A / activations as B:
//   A: lane holds Wt[n0 + (lane&15)][k=(lane>>4)*8 + j]
//   B: lane holds act[pt=lane&15][k=(lane>>4)*8 + j]
//   D = W*act -> row = neuron = (lane>>4)*4 + reg, col = point = lane&15
// Block = 16 points; wave w owns neuron half w (64 neurons) for ALL 16 points.
// __launch_bounds__(128, 2): VGPR cap 256. R14: all 16 A-frags + biases prefetched
// per layer (peak live ~180) to overlap global-load latency with the barrier.

__device__ __forceinline__ h16x2 pk(float a, float b) {
    return __builtin_amdgcn_cvt_pkrtz(a, b);          // v_cvt_pkrtz_f16_f32
}
__device__ __forceinline__ f16x4 mrg(h16x2 lo, h16x2 hi) {
    h16x4 v = __builtin_shufflevector(lo, hi, 0, 1, 2, 3);
    return __builtin_bit_cast(f16x4, v);
}

__device__ __forceinline__ float fast_tanh(float z) {
    float e = __expf(2.f * z);                 // inf for large z -> t=1; 0 for very neg -> t=-1
    return 1.f - __fdividef(2.f, e + 1.f);     // v_rcp + mul
}

__global__ void prep_weights(const float* __restrict__ W1, const float* __restrict__ W2,
                             const float* __restrict__ W3, const float* __restrict__ Wo,
                             const float* __restrict__ bo,
                             f16* __restrict__ wt1, f16* __restrict__ wt2,
                             f16* __restrict__ wt3, f16* __restrict__ wot,
                             float* __restrict__ bot)
{
    int tid    = blockIdx.x * blockDim.x + threadIdx.x;
    int stride = gridDim.x * blockDim.x;
    for (int i = tid; i < 128 * 32; i += stride) {
        int k = i >> 7, n = i & 127;
        wt1[n * 32 + k] = (f16)((k < 12) ? W1[k * 128 + n] : 0.f);
    }
    for (int i = tid; i < 128 * 128; i += stride) {
        int k = i >> 7, n = i & 127;
        wt2[n * 128 + k] = (f16)W2[i];
        wt3[n * 128 + k] = (f16)W3[i];
    }
    for (int i = tid; i < 16 * 128; i += stride) {
        int k = i >> 4, n = i & 15;
        wot[n * 128 + k] = (f16)((n < 7) ? Wo[k * 7 + n] : 0.f);
    }
    if (tid < 16) bot[tid] = (tid < 7) ? bo[tid] : 0.f;
}

// acc[c][r] = pre-activation of neuron n0q+r for point pt, channel c.
// Derivative chain in packed f16 (results are stored f16 anyway; ~1 ulp extra).
__device__ __forceinline__ void transform_store(
    f16 (*sAct)[PTS][AP], const f32x4 acc[5], const f32x4 bv,
    int pt, int n0q)
{
    float t[4], s[4];
#pragma unroll
    for (int r = 0; r < 4; ++r) {
        float z = acc[0][r] + bv[r];
        t[r] = fast_tanh(z);
        s[r] = 1.f - t[r] * t[r];
    }
    h16x2 T[2]  = { pk(t[0], t[1]), pk(t[2], t[3]) };
    h16x2 S[2]  = { pk(s[0], s[1]), pk(s[2], s[3]) };
    h16x2 A1[2] = { pk(acc[1][0], acc[1][1]), pk(acc[1][2], acc[1][3]) };
    h16x2 A2[2] = { pk(acc[2][0], acc[2][1]), pk(acc[2][2], acc[2][3]) };
    h16x2 A3[2] = { pk(acc[3][0], acc[3][1]), pk(acc[3][2], acc[3][3]) };
    h16x2 A4[2] = { pk(acc[4][0], acc[4][1]), pk(acc[4][2], acc[4][3]) };
    h16x2 TZ[2], TZZ[2], TR[2], TRR[2];
#pragma unroll
    for (int p = 0; p < 2; ++p) {
        h16x2 n2t = -(T[p] + T[p]);                    // -2t
        TZ[p]  = S[p] * A1[p];
        TR[p]  = S[p] * A3[p];
        TZZ[p] = n2t * (TZ[p] * A1[p]) + S[p] * A2[p]; // s*a2 - 2t*tz*a1
        TRR[p] = n2t * (TR[p] * A3[p]) + S[p] * A4[p];
    }
    *(f16x4*)&sAct[0][pt][n0q] = mrg(T[0], T[1]);
    *(f16x4*)&sAct[1][pt][n0q] = mrg(TZ[0], TZ[1]);
    *(f16x4*)&sAct[2][pt][n0q] = mrg(TZZ[0], TZZ[1]);
    *(f16x4*)&sAct[3][pt][n0q] = mrg(TR[0], TR[1]);
    *(f16x4*)&sAct[4][pt][n0q] = mrg(TRR[0], TRR[1]);
}

__device__ __forceinline__ void layer128(
    f16 (*sAct)[PTS][AP], const f16* __restrict__ Wt, const float* __restrict__ b,
    int half, int q, int m)
{
    // prefetch ALL weight A-frags (4 coltiles x 4 ktiles, 64 VGPR) + biases (16 VGPR)
    // for this wave's neuron half — global-load latency overlaps B-frag reads + barrier
    f16x8 A[4][4];
    f32x4 bb[4];
#pragma unroll
    for (int ct0 = 0; ct0 < 4; ++ct0) {
        const f16* wp = &Wt[((half * 4 + ct0) * 16 + m) * 128 + q * 8];
#pragma unroll
        for (int kt = 0; kt < 4; ++kt)
            A[ct0][kt] = *(const f16x8*)(wp + kt * 32);
        bb[ct0] = *(const f32x4*)&b[(half * 4 + ct0) * 16 + q * 4];
    }
    // activation B-frags: 5 ch x 4 ktiles (read once per layer, 80 VGPR)
    f16x8 Bv[5][4];
#pragma unroll
    for (int c = 0; c < 5; ++c)
#pragma unroll
        for (int kt = 0; kt < 4; ++kt)
            Bv[c][kt] = *(const f16x8*)&sAct[c][m][kt * 32 + q * 8];
    __syncthreads();   // both waves have frags in regs; safe to overwrite sAct

    const f32x4 z4 = {0.f, 0.f, 0.f, 0.f};
#pragma unroll
    for (int ct0 = 0; ct0 < 4; ++ct0) {
        const int n0 = (half * 4 + ct0) * 16;
        f32x4 acc[5];
#pragma unroll
        for (int c = 0; c < 5; ++c) acc[c] = __builtin_amdgcn_mfma_f32_16x16x32_f16(A[ct0][0], Bv[c][0], z4, 0, 0, 0);
#pragma unroll
        for (int c = 0; c < 5; ++c) acc[c] = __builtin_amdgcn_mfma_f32_16x16x32_f16(A[ct0][1], Bv[c][1], acc[c], 0, 0, 0);
#pragma unroll
        for (int c = 0; c < 5; ++c) acc[c] = __builtin_amdgcn_mfma_f32_16x16x32_f16(A[ct0][2], Bv[c][2], acc[c], 0, 0, 0);
#pragma unroll
        for (int c = 0; c < 5; ++c) acc[c] = __builtin_amdgcn_mfma_f32_16x16x32_f16(A[ct0][3], Bv[c][3], acc[c], 0, 0, 0);

        transform_store(sAct, acc, bb[ct0], m, n0 + q * 4);
    }
    __syncthreads();
}

__global__ __launch_bounds__(128, 2) void pde_main(
    const float* __restrict__ X,    // N x 4
    const int*   __restrict__ fid,  // N
    const float* __restrict__ emb,  // 4 x 8
    const float* __restrict__ b1, const float* __restrict__ b2,
    const float* __restrict__ b3,
    const f16* __restrict__ Wt1, const f16* __restrict__ Wt2,
    const f16* __restrict__ Wt3, const f16* __restrict__ Wot,
    const float* __restrict__ bot,
    float* __restrict__ partials)   // [NBLK][2]
{
    // 16-B-aligned backing store; sAct lives here, sO (padded 17) overlays after layer 3
    __shared__ f32x4 smem4[5 * PTS * AP * 2 / 16];   // 21760 B
    __shared__ float sRes[PTS][2];
    f16   (*sAct)[PTS][AP] = (f16(*)[PTS][AP])smem4;
    float (*sO)[PTS][17]   = (float(*)[PTS][17])smem4;   // 5*16*17*4 = 5440 B overlay

    const int tid  = threadIdx.x;
    const int half = tid >> 6;    // wave 0..1 = neuron half
    const int lane = tid & 63;
    const int q    = lane >> 4;   // quad 0..3
    const int m    = lane & 15;   // point / A-row
    const int p0   = blockIdx.x * PTS;

    // ---- stage layer-1 input, phase A: zero cols 0..31 of all 5ch x 16pt rows (b128) ----
    {
        const f32x4 z4 = {0.f, 0.f, 0.f, 0.f};
        for (int i = tid; i < 5 * PTS * 4; i += 128) {   // 320 stores of 16 B
            int row = i >> 2;            // c*16 + p
            int seg = i & 3;
            int c = row >> 4, p = row & 15;
            *(f32x4*)&sAct[c][p][seg * 8] = z4;
        }
    }
    __syncthreads();
    // ---- phase B: fill real values — c0 = [x0..x3, emb0..7], c1[k=1]=1, c3[k=2]=1 ----
    if (tid < PTS) {
        const int p = tid;
        f32x4 xr = *(const f32x4*)&X[(p0 + p) * 4];        // 16 B row, aligned
        const float* er = &emb[fid[p0 + p] * 8];           // 32 B row, aligned
        f32x4 e0 = *(const f32x4*)er;
        f32x4 e1 = *(const f32x4*)(er + 4);
        *(f16x4*)&sAct[0][p][0] = mrg(pk(xr.x, xr.y), pk(xr.z, xr.w));
        *(f16x4*)&sAct[0][p][4] = mrg(pk(e0.x, e0.y), pk(e0.z, e0.w));
        *(f16x4*)&sAct[0][p][8] = mrg(pk(e1.x, e1.y), pk(e1.z, e1.w));
        sAct[1][p][1] = (f16)1.f;   // e_z tangent
        sAct[3][p][2] = (f16)1.f;   // e_r tangent
    }
    __syncthreads();

    // ---- layer 1: K=32 (12 real), in-place ----
    {
        f16x8 A1v[4];
        f32x4 bb[4];
#pragma unroll
        for (int ct0 = 0; ct0 < 4; ++ct0) {
            const int n0 = (half * 4 + ct0) * 16;
            A1v[ct0] = *(const f16x8*)&Wt1[(n0 + m) * 32 + q * 8];
            bb[ct0]  = *(const f32x4*)&b1[n0 + q * 4];
        }
        f16x8 Bv[5];
#pragma unroll
        for (int c = 0; c < 5; ++c)
            Bv[c] = *(const f16x8*)&sAct[c][m][q * 8];
        __syncthreads();
        const f32x4 z4 = {0.f, 0.f, 0.f, 0.f};
#pragma unroll
        for (int ct0 = 0; ct0 < 4; ++ct0) {
            const int n0 = (half * 4 + ct0) * 16;
            f32x4 acc[5];
#pragma unroll
            for (int c = 0; c < 5; ++c)
                acc[c] = __builtin_amdgcn_mfma_f32_16x16x32_f16(A1v[ct0], Bv[c], z4, 0, 0, 0);
            transform_store(sAct, acc, bb[ct0], m, n0 + q * 4);
        }
        __syncthreads();
    }

    // ---- layers 2, 3 ----
    layer128(sAct, Wt2, b2, half, q, m);
    layer128(sAct, Wt3, b3, half, q, m);

    // ---- output head: wave 0 computes all 16 (7 real) neurons for the 16 pts ----
    f16x8 Bh[5][4];
    f16x8 Ah[4];
    f32x4 boq = {0.f, 0.f, 0.f, 0.f};
    if (half == 0) {
        const f16* wp = &Wot[m * 128 + q * 8];
#pragma unroll
        for (int kt = 0; kt < 4; ++kt)
            Ah[kt] = *(const f16x8*)(wp + kt * 32);
#pragma unroll
        for (int c = 0; c < 5; ++c)
#pragma unroll
            for (int kt = 0; kt < 4; ++kt)
                Bh[c][kt] = *(const f16x8*)&sAct[c][m][kt * 32 + q * 8];
        boq = *(const f32x4*)&bot[q * 4];
    }
    __syncthreads();   // all sAct reads done; sO overlay may now be written
    if (half == 0) {
        const f32x4 z4 = {0.f, 0.f, 0.f, 0.f};
        f32x4 acc[5];
#pragma unroll
        for (int c = 0; c < 5; ++c) acc[c] = __builtin_amdgcn_mfma_f32_16x16x32_f16(Ah[0], Bh[c][0], z4, 0, 0, 0);
#pragma unroll
        for (int c = 0; c < 5; ++c) acc[c] = __builtin_amdgcn_mfma_f32_16x16x32_f16(Ah[1], Bh[c][1], acc[c], 0, 0, 0);
#pragma unroll
        for (int c = 0; c < 5; ++c) acc[c] = __builtin_amdgcn_mfma_f32_16x16x32_f16(Ah[2], Bh[c][2], acc[c], 0, 0, 0);
#pragma unroll
        for (int c = 0; c < 5; ++c) acc[c] = __builtin_amdgcn_mfma_f32_16x16x32_f16(Ah[3], Bh[c][3], acc[c], 0, 0, 0);
        // lane m = point, regs = neurons q*4+r
#pragma unroll
        for (int c = 0; c < 5; ++c)
#pragma unroll
            for (int r = 0; r < 4; ++r)
                sO[c][m][q * 4 + r] = acc[c][r] + ((c == 0) ? boq[r] : 0.f);
    }
    __syncthreads();

    // ---- residual epilogue: one thread per point ----
    if (tid < PTS) {
        const int pt = tid;
        float o0   = sO[0][pt][0], o1  = sO[0][pt][1];
        float o0z  = sO[1][pt][0], o1z = sO[1][pt][1];
        float o0zz = sO[2][pt][0];
        float o0r  = sO[3][pt][0];
        float o0rr = sO[4][pt][0];

        float sg  = __fdividef(1.f, 1.f + __expf(-o0));
        float T   = 300.f + 2000.f * sg;
        float sp  = sg * (1.f - sg);
        float spp = sp * (1.f - 2.f * sg);
        float Tz  = 2000.f * sp * o0z;
        float Tzz = 2000.f * (spp * o0z * o0z + sp * o0zz);
        float Tr  = 2000.f * sp * o0r;
        float Trr = 2000.f * (spp * o0r * o0r + sp * o0rr);

        float fv  = ((o1 > 20.f) ? o1 : __logf(1.f + __expf(o1))) * 1e-6f;
        float s1  = __fdividef(1.f, 1.f + __expf(-o1));
        float fvz = s1 * o1z * 1e-6f;

        float y0 = sO[0][pt][2], y1 = sO[0][pt][3], y2 = sO[0][pt][4];
        float y3 = sO[0][pt][5], y4 = sO[0][pt][6];
        float mx = fmaxf(fmaxf(fmaxf(y0, y1), fmaxf(y2, y3)), y4);
        float e0 = __expf(y0 - mx), e1 = __expf(y1 - mx), e2 = __expf(y2 - mx);
        float e3 = __expf(y3 - mx), e4 = __expf(y4 - mx);
        float inv = __fdividef(1.f, e0 + e1 + e2 + e3 + e4);
        float Yp = e3 * inv;
        float Yo = e4 * inv;

        float r   = X[(p0 + pt) * 4 + 2];
        float rs  = fmaxf(r, 1e-6f);
        float rT  = __fdividef(1.f, T);
        float lap = Trr + __fdividef(Tr, rs);
        float eres = 180.f * Tz - 0.06f * lap - 0.06f * Tzz;   // RHO*CP*VZ=180, KT=0.06

        float nuc  = 1e4f * Yp * __expf(-20000.f * rT);
        float grow = 5e3f * Yp * fv * __expf(-12000.f * rT);
        float ox   = 1e5f * Yo * fv * sqrtf(T) * __expf(-16000.f * rT);
        float sres = 0.5f * fvz - nuc - grow + ox;

        sRes[pt][0] = eres * eres;
        sRes[pt][1] = sres * sres;
    }
    __syncthreads();
    // 2-thread parallel reduction (was tid0-serial over 32 values)
    if (tid < 2) {
        float s = 0.f;
#pragma unroll
        for (int p = 0; p < PTS; ++p) s += sRes[p][tid];
        partials[2 * blockIdx.x + tid] = s;
    }
}

__global__ __launch_bounds__(1024) void pde_finalize(
    const float* __restrict__ partials, float* __restrict__ out)
{
    __shared__ double rE[1024];
    __shared__ double rS[1024];
    const int tid = threadIdx.x;
    const float2* p2 = (const float2*)partials;
    double se = 0.0, ss = 0.0;
    for (int i = tid; i < NBLK; i += 1024) {
        float2 v = p2[i];
        se += (double)v.x;
        ss += (double)v.y;
    }
    rE[tid] = se; rS[tid] = ss;
    __syncthreads();
    for (int s = 512; s > 0; s >>= 1) {
        if (tid < s) { rE[tid] += rE[tid + s]; rS[tid] += rS[tid + s]; }
        __syncthreads();
    }
    if (tid == 0) {
        const double invN = 1.0 / (double)NPTS;
        float le = (float)(rE[0] * invN);
        float ls = (float)(rS[0] * invN);
        out[0] = le;
        out[1] = ls;
        out[2] = le + ls;
    }
}

extern "C" void kernel_launch(void* const* d_in, const int* in_sizes, int n_in,
                              void* d_out, int out_size, void* d_ws, size_t ws_size,
                              hipStream_t stream)
{
    const float* X   = (const float*)d_in[0];
    const int*   fid = (const int*)  d_in[1];
    const float* W1  = (const float*)d_in[2];
    const float* b1  = (const float*)d_in[3];
    const float* W2  = (const float*)d_in[4];
    const float* b2  = (const float*)d_in[5];
    const float* W3  = (const float*)d_in[6];
    const float* b3  = (const float*)d_in[7];
    const float* Wo  = (const float*)d_in[8];
    const float* bo  = (const float*)d_in[9];
    const float* emb = (const float*)d_in[10];

    f16*   wt1      = (f16*)d_ws;                  // 128*32   @ 0
    f16*   wt2      = wt1 + 128 * 32;              // 128*128  @ 8192 B
    f16*   wt3      = wt2 + 128 * 128;             // 128*128  @ 40960 B
    f16*   wot      = wt3 + 128 * 128;             // 16*128   @ 73728 B
    float* bot      = (float*)(wot + 16 * 128);    // 16 f     @ 77824 B
    float* partials = bot + 16;                    // NBLK*2 f @ 77888 B
    float* out      = (float*)d_out;

    prep_weights<<<128, 256, 0, stream>>>(W1, W2, W3, Wo, bo, wt1, wt2, wt3, wot, bot);
    pde_main<<<NBLK, 128, 0, stream>>>(X, fid, emb, b1, b2, b3,
                                       wt1, wt2, wt3, wot, bot, partials);
    pde_finalize<<<1, 1024, 0, stream>>>(partials, out);
}

// Round 15
// 241.326 us; speedup vs baseline: 1.0695x; 1.0695x over previous
//
#include <hip/hip_runtime.h>
#include <math.h>

#define NPTS 262144
#define PTS  16
#define NBLK (NPTS / PTS)   // 16384 blocks, 128 threads (2 waves) each
#define AP   136            // activation pitch in f16: 272 B -> b128-aligned rows, uniform bank spread

typedef _Float16 f16;
typedef f16    f16x4 __attribute__((ext_vector_type(4)));
typedef f16    f16x8 __attribute__((ext_vector_type(8)));
typedef __fp16 h16x2 __attribute__((ext_vector_type(2)));
typedef __fp16 h16x4 __attribute__((ext_vector_type(4)));
typedef float  f32x4 __attribute__((ext_vector_type(4)));

// MFMA 16x16x32 f16, weights as A / activations as B:
//   A: lane holds Wt[n0 + (lane&15)][k=(lane>>4)*8 + j]
//   B: lane holds act[pt=lane&15][k=(lane>>4)*8 + j]
//   D = W*act -> row = neuron = (lane>>4)*4 + reg, col = point = lane&15
// Block = 16 points; wave w owns neuron half w (64 neurons) for ALL 16 points.
// __launch_bounds__(128, 2): VGPR cap 256. R13 champion config: per-coltile A-frag
// loads inside the loop (R14's hoist-all-A-frags variant REGRESSED 190->208 us:
// compiler rescheduled anyway, occupancy fell 32->21%). (128,3) -> VGPR=72, VALU
// bloat; (128,4) -> VGPR=64 + 1.7 GB scratch spill (R11).

__device__ __forceinline__ h16x2 pk(float a, float b) {
    return __builtin_amdgcn_cvt_pkrtz(a, b);          // v_cvt_pkrtz_f16_f32
}
__device__ __forceinline__ f16x4 mrg(h16x2 lo, h16x2 hi) {
    h16x4 v = __builtin_shufflevector(lo, hi, 0, 1, 2, 3);
    return __builtin_bit_cast(f16x4, v);
}

__device__ __forceinline__ float fast_tanh(float z) {
    float e = __expf(2.f * z);                 // inf for large z -> t=1; 0 for very neg -> t=-1
    return 1.f - __fdividef(2.f, e + 1.f);     // v_rcp + mul
}

__global__ void prep_weights(const float* __restrict__ W1, const float* __restrict__ W2,
                             const float* __restrict__ W3, const float* __restrict__ Wo,
                             const float* __restrict__ bo,
                             f16* __restrict__ wt1, f16* __restrict__ wt2,
                             f16* __restrict__ wt3, f16* __restrict__ wot,
                             float* __restrict__ bot)
{
    int tid    = blockIdx.x * blockDim.x + threadIdx.x;
    int stride = gridDim.x * blockDim.x;
    for (int i = tid; i < 128 * 32; i += stride) {
        int k = i >> 7, n = i & 127;
        wt1[n * 32 + k] = (f16)((k < 12) ? W1[k * 128 + n] : 0.f);
    }
    for (int i = tid; i < 128 * 128; i += stride) {
        int k = i >> 7, n = i & 127;
        wt2[n * 128 + k] = (f16)W2[i];
        wt3[n * 128 + k] = (f16)W3[i];
    }
    for (int i = tid; i < 16 * 128; i += stride) {
        int k = i >> 4, n = i & 15;
        wot[n * 128 + k] = (f16)((n < 7) ? Wo[k * 7 + n] : 0.f);
    }
    if (tid < 16) bot[tid] = (tid < 7) ? bo[tid] : 0.f;
}

// acc[c][r] = pre-activation of neuron n0q+r for point pt, channel c.
// Derivative chain in packed f16 (results are stored f16 anyway; ~1 ulp extra).
__device__ __forceinline__ void transform_store(
    f16 (*sAct)[PTS][AP], const f32x4 acc[5], const f32x4 bv,
    int pt, int n0q)
{
    float t[4], s[4];
#pragma unroll
    for (int r = 0; r < 4; ++r) {
        float z = acc[0][r] + bv[r];
        t[r] = fast_tanh(z);
        s[r] = 1.f - t[r] * t[r];
    }
    h16x2 T[2]  = { pk(t[0], t[1]), pk(t[2], t[3]) };
    h16x2 S[2]  = { pk(s[0], s[1]), pk(s[2], s[3]) };
    h16x2 A1[2] = { pk(acc[1][0], acc[1][1]), pk(acc[1][2], acc[1][3]) };
    h16x2 A2[2] = { pk(acc[2][0], acc[2][1]), pk(acc[2][2], acc[2][3]) };
    h16x2 A3[2] = { pk(acc[3][0], acc[3][1]), pk(acc[3][2], acc[3][3]) };
    h16x2 A4[2] = { pk(acc[4][0], acc[4][1]), pk(acc[4][2], acc[4][3]) };
    h16x2 TZ[2], TZZ[2], TR[2], TRR[2];
#pragma unroll
    for (int p = 0; p < 2; ++p) {
        h16x2 n2t = -(T[p] + T[p]);                    // -2t
        TZ[p]  = S[p] * A1[p];
        TR[p]  = S[p] * A3[p];
        TZZ[p] = n2t * (TZ[p] * A1[p]) + S[p] * A2[p]; // s*a2 - 2t*tz*a1
        TRR[p] = n2t * (TR[p] * A3[p]) + S[p] * A4[p];
    }
    *(f16x4*)&sAct[0][pt][n0q] = mrg(T[0], T[1]);
    *(f16x4*)&sAct[1][pt][n0q] = mrg(TZ[0], TZ[1]);
    *(f16x4*)&sAct[2][pt][n0q] = mrg(TZZ[0], TZZ[1]);
    *(f16x4*)&sAct[3][pt][n0q] = mrg(TR[0], TR[1]);
    *(f16x4*)&sAct[4][pt][n0q] = mrg(TRR[0], TRR[1]);
}

__device__ __forceinline__ void layer128(
    f16 (*sAct)[PTS][AP], const f16* __restrict__ Wt, const float* __restrict__ b,
    int half, int q, int m)
{
    // activation B-frags: 5 ch x 4 ktiles (read once per layer)
    f16x8 Bv[5][4];
#pragma unroll
    for (int c = 0; c < 5; ++c)
#pragma unroll
        for (int kt = 0; kt < 4; ++kt)
            Bv[c][kt] = *(const f16x8*)&sAct[c][m][kt * 32 + q * 8];
    __syncthreads();   // both waves have B-frags in regs; safe to overwrite sAct

    const f32x4 z4 = {0.f, 0.f, 0.f, 0.f};
#pragma unroll
    for (int ct0 = 0; ct0 < 4; ++ct0) {
        const int n0 = (half * 4 + ct0) * 16;
        const f16* wp = &Wt[(n0 + m) * 128 + q * 8];
        f16x8 A0 = *(const f16x8*)(wp);
        f16x8 A1 = *(const f16x8*)(wp + 32);
        f16x8 A2 = *(const f16x8*)(wp + 64);
        f16x8 A3 = *(const f16x8*)(wp + 96);
        f32x4 bb = *(const f32x4*)&b[n0 + q * 4];
        f32x4 acc[5];
#pragma unroll
        for (int c = 0; c < 5; ++c) acc[c] = __builtin_amdgcn_mfma_f32_16x16x32_f16(A0, Bv[c][0], z4, 0, 0, 0);
#pragma unroll
        for (int c = 0; c < 5; ++c) acc[c] = __builtin_amdgcn_mfma_f32_16x16x32_f16(A1, Bv[c][1], acc[c], 0, 0, 0);
#pragma unroll
        for (int c = 0; c < 5; ++c) acc[c] = __builtin_amdgcn_mfma_f32_16x16x32_f16(A2, Bv[c][2], acc[c], 0, 0, 0);
#pragma unroll
        for (int c = 0; c < 5; ++c) acc[c] = __builtin_amdgcn_mfma_f32_16x16x32_f16(A3, Bv[c][3], acc[c], 0, 0, 0);

        transform_store(sAct, acc, bb, m, n0 + q * 4);
    }
    __syncthreads();
}

__global__ __launch_bounds__(128, 2) void pde_main(
    const float* __restrict__ X,    // N x 4
    const int*   __restrict__ fid,  // N
    const float* __restrict__ emb,  // 4 x 8
    const float* __restrict__ b1, const float* __restrict__ b2,
    const float* __restrict__ b3,
    const f16* __restrict__ Wt1, const f16* __restrict__ Wt2,
    const f16* __restrict__ Wt3, const f16* __restrict__ Wot,
    const float* __restrict__ bot,
    float* __restrict__ partials)   // [NBLK][2]
{
    // 16-B-aligned backing store; sAct lives here, sO (padded 17) overlays after layer 3
    __shared__ f32x4 smem4[5 * PTS * AP * 2 / 16];   // 21760 B
    __shared__ float sRes[PTS][2];
    f16   (*sAct)[PTS][AP] = (f16(*)[PTS][AP])smem4;
    float (*sO)[PTS][17]   = (float(*)[PTS][17])smem4;   // 5*16*17*4 = 5440 B overlay

    const int tid  = threadIdx.x;
    const int half = tid >> 6;    // wave 0..1 = neuron half
    const int lane = tid & 63;
    const int q    = lane >> 4;   // quad 0..3
    const int m    = lane & 15;   // point / A-row
    const int p0   = blockIdx.x * PTS;

    // ---- stage layer-1 input, phase A: zero cols 0..31 of all 5ch x 16pt rows (b128) ----
    {
        const f32x4 z4 = {0.f, 0.f, 0.f, 0.f};
        for (int i = tid; i < 5 * PTS * 4; i += 128) {   // 320 stores of 16 B
            int row = i >> 2;            // c*16 + p
            int seg = i & 3;
            int c = row >> 4, p = row & 15;
            *(f32x4*)&sAct[c][p][seg * 8] = z4;
        }
    }
    __syncthreads();
    // ---- phase B: fill real values — c0 = [x0..x3, emb0..7], c1[k=1]=1, c3[k=2]=1 ----
    if (tid < PTS) {
        const int p = tid;
        f32x4 xr = *(const f32x4*)&X[(p0 + p) * 4];        // 16 B row, aligned
        const float* er = &emb[fid[p0 + p] * 8];           // 32 B row, aligned
        f32x4 e0 = *(const f32x4*)er;
        f32x4 e1 = *(const f32x4*)(er + 4);
        *(f16x4*)&sAct[0][p][0] = mrg(pk(xr.x, xr.y), pk(xr.z, xr.w));
        *(f16x4*)&sAct[0][p][4] = mrg(pk(e0.x, e0.y), pk(e0.z, e0.w));
        *(f16x4*)&sAct[0][p][8] = mrg(pk(e1.x, e1.y), pk(e1.z, e1.w));
        sAct[1][p][1] = (f16)1.f;   // e_z tangent
        sAct[3][p][2] = (f16)1.f;   // e_r tangent
    }
    __syncthreads();

    // ---- layer 1: K=32 (12 real), in-place ----
    {
        f16x8 Bv[5];
#pragma unroll
        for (int c = 0; c < 5; ++c)
            Bv[c] = *(const f16x8*)&sAct[c][m][q * 8];
        __syncthreads();
        const f32x4 z4 = {0.f, 0.f, 0.f, 0.f};
#pragma unroll
        for (int ct0 = 0; ct0 < 4; ++ct0) {
            const int n0 = (half * 4 + ct0) * 16;
            f16x8 A0 = *(const f16x8*)&Wt1[(n0 + m) * 32 + q * 8];
            f32x4 bb = *(const f32x4*)&b1[n0 + q * 4];
            f32x4 acc[5];
#pragma unroll
            for (int c = 0; c < 5; ++c)
                acc[c] = __builtin_amdgcn_mfma_f32_16x16x32_f16(A0, Bv[c], z4, 0, 0, 0);
            transform_store(sAct, acc, bb, m, n0 + q * 4);
        }
        __syncthreads();
    }

    // ---- layers 2, 3 ----
    layer128(sAct, Wt2, b2, half, q, m);
    layer128(sAct, Wt3, b3, half, q, m);

    // ---- output head: wave 0 computes all 16 (7 real) neurons for the 16 pts ----
    f16x8 Bh[5][4];
    f32x4 boq = {0.f, 0.f, 0.f, 0.f};
    if (half == 0) {
#pragma unroll
        for (int c = 0; c < 5; ++c)
#pragma unroll
            for (int kt = 0; kt < 4; ++kt)
                Bh[c][kt] = *(const f16x8*)&sAct[c][m][kt * 32 + q * 8];
        boq = *(const f32x4*)&bot[q * 4];
    }
    __syncthreads();   // all sAct reads done; sO overlay may now be written
    if (half == 0) {
        const f16* wp = &Wot[m * 128 + q * 8];
        f16x8 A0 = *(const f16x8*)(wp);
        f16x8 A1 = *(const f16x8*)(wp + 32);
        f16x8 A2 = *(const f16x8*)(wp + 64);
        f16x8 A3 = *(const f16x8*)(wp + 96);
        const f32x4 z4 = {0.f, 0.f, 0.f, 0.f};
        f32x4 acc[5];
#pragma unroll
        for (int c = 0; c < 5; ++c) acc[c] = __builtin_amdgcn_mfma_f32_16x16x32_f16(A0, Bh[c][0], z4, 0, 0, 0);
#pragma unroll
        for (int c = 0; c < 5; ++c) acc[c] = __builtin_amdgcn_mfma_f32_16x16x32_f16(A1, Bh[c][1], acc[c], 0, 0, 0);
#pragma unroll
        for (int c = 0; c < 5; ++c) acc[c] = __builtin_amdgcn_mfma_f32_16x16x32_f16(A2, Bh[c][2], acc[c], 0, 0, 0);
#pragma unroll
        for (int c = 0; c < 5; ++c) acc[c] = __builtin_amdgcn_mfma_f32_16x16x32_f16(A3, Bh[c][3], acc[c], 0, 0, 0);
        // lane m = point, regs = neurons q*4+r
#pragma unroll
        for (int c = 0; c < 5; ++c)
#pragma unroll
            for (int r = 0; r < 4; ++r)
                sO[c][m][q * 4 + r] = acc[c][r] + ((c == 0) ? boq[r] : 0.f);
    }
    __syncthreads();

    // ---- residual epilogue: one thread per point ----
    if (tid < PTS) {
        const int pt = tid;
        float o0   = sO[0][pt][0], o1  = sO[0][pt][1];
        float o0z  = sO[1][pt][0], o1z = sO[1][pt][1];
        float o0zz = sO[2][pt][0];
        float o0r  = sO[3][pt][0];
        float o0rr = sO[4][pt][0];

        float sg  = __fdividef(1.f, 1.f + __expf(-o0));
        float T   = 300.f + 2000.f * sg;
        float sp  = sg * (1.f - sg);
        float spp = sp * (1.f - 2.f * sg);
        float Tz  = 2000.f * sp * o0z;
        float Tzz = 2000.f * (spp * o0z * o0z + sp * o0zz);
        float Tr  = 2000.f * sp * o0r;
        float Trr = 2000.f * (spp * o0r * o0r + sp * o0rr);

        float fv  = ((o1 > 20.f) ? o1 : __logf(1.f + __expf(o1))) * 1e-6f;
        float s1  = __fdividef(1.f, 1.f + __expf(-o1));
        float fvz = s1 * o1z * 1e-6f;

        float y0 = sO[0][pt][2], y1 = sO[0][pt][3], y2 = sO[0][pt][4];
        float y3 = sO[0][pt][5], y4 = sO[0][pt][6];
        float mx = fmaxf(fmaxf(fmaxf(y0, y1), fmaxf(y2, y3)), y4);
        float e0 = __expf(y0 - mx), e1 = __expf(y1 - mx), e2 = __expf(y2 - mx);
        float e3 = __expf(y3 - mx), e4 = __expf(y4 - mx);
        float inv = __fdividef(1.f, e0 + e1 + e2 + e3 + e4);
        float Yp = e3 * inv;
        float Yo = e4 * inv;

        float r   = X[(p0 + pt) * 4 + 2];
        float rs  = fmaxf(r, 1e-6f);
        float rT  = __fdividef(1.f, T);
        float lap = Trr + __fdividef(Tr, rs);
        float eres = 180.f * Tz - 0.06f * lap - 0.06f * Tzz;   // RHO*CP*VZ=180, KT=0.06

        float nuc  = 1e4f * Yp * __expf(-20000.f * rT);
        float grow = 5e3f * Yp * fv * __expf(-12000.f * rT);
        float ox   = 1e5f * Yo * fv * sqrtf(T) * __expf(-16000.f * rT);
        float sres = 0.5f * fvz - nuc - grow + ox;

        sRes[pt][0] = eres * eres;
        sRes[pt][1] = sres * sres;
    }
    __syncthreads();
    if (tid == 0) {
        float se = 0.f, ss = 0.f;
#pragma unroll
        for (int p = 0; p < PTS; ++p) { se += sRes[p][0]; ss += sRes[p][1]; }
        partials[2 * blockIdx.x]     = se;
        partials[2 * blockIdx.x + 1] = ss;
    }
}

__global__ __launch_bounds__(1024) void pde_finalize(
    const float* __restrict__ partials, float* __restrict__ out)
{
    __shared__ double rE[1024];
    __shared__ double rS[1024];
    const int tid = threadIdx.x;
    const float2* p2 = (const float2*)partials;
    double se = 0.0, ss = 0.0;
    for (int i = tid; i < NBLK; i += 1024) {
        float2 v = p2[i];
        se += (double)v.x;
        ss += (double)v.y;
    }
    rE[tid] = se; rS[tid] = ss;
    __syncthreads();
    for (int s = 512; s > 0; s >>= 1) {
        if (tid < s) { rE[tid] += rE[tid + s]; rS[tid] += rS[tid + s]; }
        __syncthreads();
    }
    if (tid == 0) {
        const double invN = 1.0 / (double)NPTS;
        float le = (float)(rE[0] * invN);
        float ls = (float)(rS[0] * invN);
        out[0] = le;
        out[1] = ls;
        out[2] = le + ls;
    }
}

extern "C" void kernel_launch(void* const* d_in, const int* in_sizes, int n_in,
                              void* d_out, int out_size, void* d_ws, size_t ws_size,
                              hipStream_t stream)
{
    const float* X   = (const float*)d_in[0];
    const int*   fid = (const int*)  d_in[1];
    const float* W1  = (const float*)d_in[2];
    const float* b1  = (const float*)d_in[3];
    const float* W2  = (const float*)d_in[4];
    const float* b2  = (const float*)d_in[5];
    const float* W3  = (const float*)d_in[6];
    const float* b3  = (const float*)d_in[7];
    const float* Wo  = (const float*)d_in[8];
    const float* bo  = (const float*)d_in[9];
    const float* emb = (const float*)d_in[10];

    f16*   wt1      = (f16*)d_ws;                  // 128*32   @ 0
    f16*   wt2      = wt1 + 128 * 32;              // 128*128  @ 8192 B
    f16*   wt3      = wt2 + 128 * 128;             // 128*128  @ 40960 B
    f16*   wot      = wt3 + 128 * 128;             // 16*128   @ 73728 B
    float* bot      = (float*)(wot + 16 * 128);    // 16 f     @ 77824 B
    float* partials = bot + 16;                    // NBLK*2 f @ 77888 B
    float* out      = (float*)d_out;

    prep_weights<<<128, 256, 0, stream>>>(W1, W2, W3, Wo, bo, wt1, wt2, wt3, wot, bot);
    pde_main<<<NBLK, 128, 0, stream>>>(X, fid, emb, b1, b2, b3,
                                       wt1, wt2, wt3, wot, bot, partials);
    pde_finalize<<<1, 1024, 0, stream>>>(partials, out);
}